// Round 4
// baseline (332.616 us; speedup 1.0000x reference)
//
#include <hip/hip_runtime.h>

typedef unsigned short UB;
typedef __attribute__((ext_vector_type(8))) __bf16 bf16x8;
typedef __attribute__((ext_vector_type(4))) __bf16 bf16x4;
typedef __attribute__((ext_vector_type(4))) float floatx4;
typedef __attribute__((ext_vector_type(4))) short short4v;

#define GAS __attribute__((address_space(1)))
#define LAS __attribute__((address_space(3)))

// ---------- helpers ----------
__device__ __forceinline__ UB f2bf(float f) {
    unsigned int x = __float_as_uint(f);
    unsigned int r = (x + 0x7fffu + ((x >> 16) & 1u)) >> 16;
    return (UB)r;
}

// fast gelu: tanh via exp2 + rcp (~11 VALU ops, err ~1e-6)
__device__ __forceinline__ float gelu_f(float v) {
    const float K = 2.3022083f;            // 2*sqrt(2/pi)*log2(e)
    const float v2 = v * v;
    const float u = v * fmaf(0.044715f, v2, 1.0f);
    float arg = K * u;
    arg = fminf(fmaxf(arg, -80.f), 80.f);  // v_med3
    const float e = __builtin_amdgcn_exp2f(arg);
    const float th = (e - 1.0f) * __builtin_amdgcn_rcpf(e + 1.0f);
    const float hv = 0.5f * v;
    return fmaf(hv, th, hv);
}

// async 16B global -> LDS (lds dest: wave-uniform base + lane*16)
__device__ __forceinline__ void gload16(const UB* g, UB* l) {
    __builtin_amdgcn_global_load_lds((const GAS unsigned int*)g,
                                     (LAS unsigned int*)l, 16, 0, 0);
}

// ---------- fp32 [K][N] -> bf16 [N][K] transpose ----------
__global__ __launch_bounds__(256)
void transpose_w_kernel(const float* __restrict__ W, UB* __restrict__ Wt, int K, int N)
{
    __shared__ float tile[32][33];
    const int n0 = blockIdx.x * 32;
    const int k0 = blockIdx.y * 32;
    const int x = threadIdx.x & 31;
    const int y = threadIdx.x >> 5;  // 0..7
#pragma unroll
    for (int j = 0; j < 32; j += 8)
        tile[y + j][x] = W[(size_t)(k0 + y + j) * N + n0 + x];
    __syncthreads();
#pragma unroll
    for (int j = 0; j < 32; j += 8)
        Wt[(size_t)(n0 + y + j) * K + k0 + x] = f2bf(tile[x][y + j]);
}

// ---------- LayerNorm fp32 -> bf16, one block per row, E=1024 ----------
__global__ __launch_bounds__(256)
void layernorm_kernel(const float* __restrict__ x, const float* __restrict__ g,
                      const float* __restrict__ bta, UB* __restrict__ out)
{
    __shared__ float red[8];
    const int row = blockIdx.x;
    const float* xr = x + (size_t)row * 1024;
    float v[4];
    float sum = 0.f, sumsq = 0.f;
#pragma unroll
    for (int i = 0; i < 4; ++i) {
        v[i] = xr[threadIdx.x + i * 256];
        sum += v[i];
        sumsq += v[i] * v[i];
    }
#pragma unroll
    for (int off = 32; off > 0; off >>= 1) {
        sum += __shfl_down(sum, off);
        sumsq += __shfl_down(sumsq, off);
    }
    const int w = threadIdx.x >> 6;
    if ((threadIdx.x & 63) == 0) { red[w * 2] = sum; red[w * 2 + 1] = sumsq; }
    __syncthreads();
    if (threadIdx.x == 0) {
        float s = 0.f, s2 = 0.f;
#pragma unroll
        for (int i = 0; i < 4; ++i) { s += red[i * 2]; s2 += red[i * 2 + 1]; }
        red[0] = s * (1.0f / 1024.0f);
        red[1] = s2 * (1.0f / 1024.0f);
    }
    __syncthreads();
    const float mu = red[0];
    const float var = red[1] - mu * mu;
    const float rs = rsqrtf(var + 1e-5f);
#pragma unroll
    for (int i = 0; i < 4; ++i) {
        const int e = threadIdx.x + i * 256;
        out[(size_t)row * 1024 + e] = f2bf((v[i] - mu) * rs * g[e] + bta[e]);
    }
}

// ---------- reduce: tgt += partial + res + bias  (fp32, N=1024) ----------
__global__ __launch_bounds__(256)
void reduce_kernel(float* __restrict__ tgt, const float* __restrict__ p_lo,
                   const float* __restrict__ p_hi, int rowSplit,
                   const float* __restrict__ res, const float* __restrict__ bias)
{
    const int i = blockIdx.x * 256 + threadIdx.x;  // float4 index
    const int row = i >> 8;
    const int col4 = i & 255;
    const float* p = (row < rowSplit) ? (p_lo + (size_t)row * 1024)
                                      : (p_hi + (size_t)(row - rowSplit) * 1024);
    const float4 t = ((const float4*)&tgt[(size_t)row * 1024])[col4];
    const float4 q = ((const float4*)p)[col4];
    const float4 r = ((const float4*)&res[(size_t)row * 1024])[col4];
    const float4 b = ((const float4*)bias)[col4];
    float4 o = make_float4(t.x + q.x + r.x + b.x, t.y + q.y + r.y + b.y,
                           t.z + q.z + r.z + b.z, t.w + q.w + r.w + b.w);
    ((float4*)&tgt[(size_t)row * 1024])[col4] = o;
}

// ---------- fused: x1 = x1 + partial + res + bias (store fp32), then LN -> bf16 ----------
__global__ __launch_bounds__(256)
void reduce_ln_kernel(float* __restrict__ tgt, const float* __restrict__ p_lo,
                      const float* __restrict__ p_hi, int rowSplit,
                      const float* __restrict__ res, const float* __restrict__ bias,
                      const float* __restrict__ g, const float* __restrict__ bta,
                      UB* __restrict__ outb)
{
    __shared__ float red[8];
    const int row = blockIdx.x;
    const int col4 = threadIdx.x;                  // float4 column
    const float* p = (row < rowSplit) ? (p_lo + (size_t)row * 1024)
                                      : (p_hi + (size_t)(row - rowSplit) * 1024);
    const float4 t = ((const float4*)&tgt[(size_t)row * 1024])[col4];
    const float4 q = ((const float4*)p)[col4];
    const float4 r = ((const float4*)&res[(size_t)row * 1024])[col4];
    const float4 b = ((const float4*)bias)[col4];
    float s[4];
    s[0] = t.x + q.x + r.x + b.x; s[1] = t.y + q.y + r.y + b.y;
    s[2] = t.z + q.z + r.z + b.z; s[3] = t.w + q.w + r.w + b.w;
    ((float4*)&tgt[(size_t)row * 1024])[col4] = make_float4(s[0], s[1], s[2], s[3]);

    float sum = s[0] + s[1] + s[2] + s[3];
    float sumsq = s[0]*s[0] + s[1]*s[1] + s[2]*s[2] + s[3]*s[3];
#pragma unroll
    for (int off = 32; off > 0; off >>= 1) {
        sum += __shfl_down(sum, off);
        sumsq += __shfl_down(sumsq, off);
    }
    const int w = threadIdx.x >> 6;
    if ((threadIdx.x & 63) == 0) { red[w * 2] = sum; red[w * 2 + 1] = sumsq; }
    __syncthreads();
    if (threadIdx.x == 0) {
        float a = 0.f, a2 = 0.f;
#pragma unroll
        for (int i = 0; i < 4; ++i) { a += red[i * 2]; a2 += red[i * 2 + 1]; }
        red[0] = a * (1.0f / 1024.0f);
        red[1] = a2 * (1.0f / 1024.0f);
    }
    __syncthreads();
    const float mu = red[0];
    const float var = red[1] - mu * mu;
    const float rs = rsqrtf(var + 1e-5f);
    const float4 gg = ((const float4*)g)[col4];
    const float4 bb = ((const float4*)bta)[col4];
    UB o4[4];
    o4[0] = f2bf((s[0] - mu) * rs * gg.x + bb.x);
    o4[1] = f2bf((s[1] - mu) * rs * gg.y + bb.y);
    o4[2] = f2bf((s[2] - mu) * rs * gg.z + bb.z);
    o4[3] = f2bf((s[3] - mu) * rs * gg.w + bb.w);
    *(ushort4*)&outb[(size_t)row * 1024 + col4 * 4] = *(ushort4*)o4;
}

// ---------- GEMM v4: LDS-staged, BK=64, XOR-8 swizzle (conflict-free b128 reads)
// BM=128 x BN x 64; 4 waves; wave tile 64 x (BN/2).
// MODE 0: bf16 +bias   MODE 2: bf16 gelu(+bias)   MODE 4: split-K fp32 partial
// OCC: min waves/EU; OCC=4 (<=128 unified regs) enables 4 blocks/CU at BN=128.
template<int MODE, int BN, int OCC>
__global__ __launch_bounds__(256, OCC)
void gemm_bt_kernel(const UB* __restrict__ A, const UB* __restrict__ Bt,
                    const float* __restrict__ bias,
                    void* __restrict__ outp, float* __restrict__ pz_lo,
                    float* __restrict__ pz_hi, int rowSplit,
                    int M, int N, int K, int kLen)
{
    constexpr int NI = BN / 32;        // n-frags per wave per kk (4 or 8)
    constexpr int NB = BN / 32;        // B DMA instrs per thread (4 or 8)
    __shared__ UB As[128 * 64];        // 16 KB
    __shared__ UB Bs[BN * 64];         // 16/32 KB
    const int tid = threadIdx.x;
    const int lane = tid & 63;
    const int w = tid >> 6;
    const int l15 = lane & 15;
    const int lq = lane >> 4;
    const int wm = (w >> 1) * 64;
    const int wn = (w & 1) * (BN / 2);
    const int m0 = blockIdx.y * 128;
    const int n0 = blockIdx.x * BN;
    const int kBase = blockIdx.z * kLen;
    const int e7 = l15 & 7;            // row&7 for all fragment rows

    // DMA pointers: A 4 instrs (1024 chunks), B NB instrs
    const UB* aG[4];
    UB* aL[4];
#pragma unroll
    for (int j = 0; j < 4; ++j) {
        const int c = j * 256 + w * 64 + lane;
        const int row = c >> 3;
        const int g = (c & 7) ^ (row & 7);
        aG[j] = A + (size_t)(m0 + row) * K + kBase + g * 8;
        aL[j] = As + (size_t)(j * 256 + w * 64) * 8;
    }
    const UB* bG[NB];
    UB* bL[NB];
#pragma unroll
    for (int j = 0; j < NB; ++j) {
        const int c = j * 256 + w * 64 + lane;
        const int row = c >> 3;
        const int g = (c & 7) ^ (row & 7);
        bG[j] = Bt + (size_t)(n0 + row) * K + kBase + g * 8;
        bL[j] = Bs + (size_t)(j * 256 + w * 64) * 8;
    }

    floatx4 acc[4][NI];
#pragma unroll
    for (int i = 0; i < 4; ++i)
#pragma unroll
        for (int j = 0; j < NI; ++j)
            acc[i][j] = (floatx4){0.f, 0.f, 0.f, 0.f};

    for (int ks = 0; ks < kLen; ks += 64) {
        __syncthreads();
#pragma unroll
        for (int j = 0; j < 4; ++j) gload16(aG[j] + ks, aL[j]);
#pragma unroll
        for (int j = 0; j < NB; ++j) gload16(bG[j] + ks, bL[j]);
        __syncthreads();

#pragma unroll
        for (int kk = 0; kk < 2; ++kk) {
            bf16x8 af[4], bfr[NI];
#pragma unroll
            for (int mi = 0; mi < 4; ++mi)
                af[mi] = *(const bf16x8*)&As[(wm + mi * 16 + l15) * 64 + (((kk * 4 + lq) ^ e7) * 8)];
#pragma unroll
            for (int ni = 0; ni < NI; ++ni)
                bfr[ni] = *(const bf16x8*)&Bs[(wn + ni * 16 + l15) * 64 + (((kk * 4 + lq) ^ e7) * 8)];
#pragma unroll
            for (int mi = 0; mi < 4; ++mi)
#pragma unroll
                for (int ni = 0; ni < NI; ++ni)
                    acc[mi][ni] = __builtin_amdgcn_mfma_f32_16x16x32_bf16(af[mi], bfr[ni], acc[mi][ni], 0, 0, 0);
        }
    }

    if (MODE == 4) {
        float* base;
        int roff;
        if (blockIdx.z == 0) { base = (float*)outp; roff = 0; }
        else if (m0 < rowSplit) { base = pz_lo; roff = 0; }
        else { base = pz_hi; roff = rowSplit; }
#pragma unroll
        for (int mi = 0; mi < 4; ++mi)
#pragma unroll
            for (int ni = 0; ni < NI; ++ni)
#pragma unroll
                for (int r = 0; r < 4; ++r) {
                    const int row = m0 + wm + mi * 16 + lq * 4 + r - roff;
                    const int col = n0 + wn + ni * 16 + l15;
                    base[(size_t)row * N + col] = acc[mi][ni][r];
                }
    } else {
#pragma unroll
        for (int mi = 0; mi < 4; ++mi)
#pragma unroll
            for (int ni = 0; ni < NI; ++ni)
#pragma unroll
                for (int r = 0; r < 4; ++r) {
                    const int row = m0 + wm + mi * 16 + lq * 4 + r;
                    const int col = n0 + wn + ni * 16 + l15;
                    float v = acc[mi][ni][r] + bias[col];
                    if (MODE == 2) v = gelu_f(v);
                    ((UB*)outp)[(size_t)row * N + col] = f2bf(v);
                }
    }
}

// ---------- Flash attention v7 (causal): S^T trick, register-only P.
// v6 base (dbuf K/V LDS, depth-2 reg prefetch, one raw barrier/K-tile) plus:
//  - V-pack via v_perm (1 op/slot instead of ~4 bitops)
//  - max3-tree mx reduce (depth 3) + pairwise-tree sl reduce (depth 4)
//  - defer-max (T13, thr=8, wave-uniform __any): skip al-exp2 + 16-mul
//    O-rescale when running max grows < 8/log2e. P bounded by 2^8; fp32
//    accum fine. First tile always rescales (al = exp2(-1e30-m) = 0).
//  - s_setprio(1) around S-MFMA and PV-MFMA clusters (T5)
#define FLASH_BODY(KT, S, KA, KB, VA, VB)                                            \
    {                                                                                \
        const int kt_ = (KT);                                                        \
        /* stage tile kt into LDS buf S (compiler waits vmcnt for KA..VB only) */    \
        *(uint4*)&Ks[S][krow][kch8] = KA;                                            \
        *(uint4*)&Ks[S][krow + 32][kch8] = KB;                                       \
        {                                                                            \
            const unsigned* aw = (const unsigned*)&VA;                               \
            const unsigned* bw = (const unsigned*)&VB;                               \
            _Pragma("unroll")                                                        \
            for (int j = 0; j < 8; ++j)                                              \
                VtsP[S][vd0 + j][vcol] = __builtin_amdgcn_perm(                      \
                    bw[j >> 1], aw[j >> 1], (j & 1) ? 0x07060302u : 0x05040100u);    \
        }                                                                            \
        /* refill this reg set with tile kt+2 (clamped to qt) */                     \
        {                                                                            \
            const int t2 = (kt_ + 2 <= qt) ? (kt_ + 2) : qt;                         \
            const size_t off = (size_t)t2 * 196608;  /* 64*3072 */                   \
            KA = *(const uint4*)(kp0 + off);                                         \
            KB = *(const uint4*)(kp1 + off);                                         \
            VA = *(const uint4*)(vp0 + off);                                         \
            VB = *(const uint4*)(vp1 + off);                                         \
        }                                                                            \
        /* single barrier: drain LDS writes only; vmcnt stays in flight */           \
        asm volatile("s_waitcnt lgkmcnt(0)\n\ts_barrier" ::: "memory");              \
        const bool needmask = (kt_ == qt);                                           \
        floatx4 sacc[4];                                                             \
        __builtin_amdgcn_s_setprio(1);                                               \
        _Pragma("unroll")                                                            \
        for (int nj = 0; nj < 4; ++nj) {                                             \
            bf16x8 ak0 = *(const bf16x8*)&Ks[S][nj * 16 + l15][lq8];                 \
            bf16x8 ak1 = *(const bf16x8*)&Ks[S][nj * 16 + l15][32 + lq8];            \
            floatx4 acc = (floatx4){0.f, 0.f, 0.f, 0.f};                             \
            acc = __builtin_amdgcn_mfma_f32_16x16x32_bf16(ak0, qf[0], acc, 0, 0, 0); \
            acc = __builtin_amdgcn_mfma_f32_16x16x32_bf16(ak1, qf[1], acc, 0, 0, 0); \
            sacc[nj] = acc;                                                          \
        }                                                                            \
        __builtin_amdgcn_s_setprio(0);                                               \
        if (needmask) {                                                              \
            _Pragma("unroll")                                                        \
            for (int nj = 0; nj < 4; ++nj)                                           \
                _Pragma("unroll")                                                    \
                for (int r = 0; r < 4; ++r) {                                        \
                    const int kcol = kt_ * 64 + nj * 16 + lq * 4 + r;                \
                    if (kcol > qrow) sacc[nj][r] = -1e30f;                           \
                }                                                                    \
        }                                                                            \
        {                                                                            \
            /* max3-fused tree reduce, depth 3 */                                    \
            const float t0 = fmaxf(fmaxf(sacc[0][0], sacc[0][1]), sacc[0][2]);       \
            const float t1 = fmaxf(fmaxf(sacc[0][3], sacc[1][0]), sacc[1][1]);       \
            const float t2m = fmaxf(fmaxf(sacc[1][2], sacc[1][3]), sacc[2][0]);      \
            const float t3 = fmaxf(fmaxf(sacc[2][1], sacc[2][2]), sacc[2][3]);       \
            const float t4 = fmaxf(fmaxf(sacc[3][0], sacc[3][1]), sacc[3][2]);       \
            const float u0 = fmaxf(fmaxf(t0, t1), t2m);                              \
            const float u1 = fmaxf(fmaxf(t3, t4), sacc[3][3]);                       \
            float mx = fmaxf(u0, u1);                                                \
            mx = fmaxf(mx, __shfl_xor(mx, 16));                                      \
            mx = fmaxf(mx, __shfl_xor(mx, 32));                                      \
            const float mxs = mx * SCL;                                              \
            /* defer-max: only rescale when max grew by > 8 (wave-uniform) */        \
            if (__any(mxs > m_r + 8.0f)) {                                           \
                const float mnew = fmaxf(m_r, mxs);                                  \
                const float al = __builtin_amdgcn_exp2f(m_r - mnew);                 \
                m_r = mnew;                                                          \
                l_r *= al;                                                           \
                _Pragma("unroll")                                                    \
                for (int nd = 0; nd < 4; ++nd)                                       \
                    _Pragma("unroll")                                                \
                    for (int r = 0; r < 4; ++r) o[nd][r] *= al;                      \
            }                                                                        \
            _Pragma("unroll")                                                        \
            for (int nj = 0; nj < 4; ++nj)                                           \
                _Pragma("unroll")                                                    \
                for (int r = 0; r < 4; ++r)                                          \
                    sacc[nj][r] = __builtin_amdgcn_exp2f(fmaf(sacc[nj][r], SCL, -m_r)); \
            /* pairwise add tree, depth 4 */                                         \
            const float a0 = sacc[0][0] + sacc[0][1], a1 = sacc[0][2] + sacc[0][3];  \
            const float a2 = sacc[1][0] + sacc[1][1], a3 = sacc[1][2] + sacc[1][3];  \
            const float a4 = sacc[2][0] + sacc[2][1], a5 = sacc[2][2] + sacc[2][3];  \
            const float a6 = sacc[3][0] + sacc[3][1], a7 = sacc[3][2] + sacc[3][3];  \
            float sl = ((a0 + a1) + (a2 + a3)) + ((a4 + a5) + (a6 + a7));            \
            sl += __shfl_xor(sl, 16);                                                \
            sl += __shfl_xor(sl, 32);                                                \
            l_r += sl;                                                               \
        }                                                                            \
        __builtin_amdgcn_s_setprio(1);                                               \
        _Pragma("unroll")                                                            \
        for (int nj = 0; nj < 4; ++nj) {                                             \
            union { unsigned int u[2]; short4v s; } bp;                              \
            bp.u[0] = __builtin_amdgcn_perm(__float_as_uint(sacc[nj][1]),            \
                                            __float_as_uint(sacc[nj][0]), 0x07060302u); \
            bp.u[1] = __builtin_amdgcn_perm(__float_as_uint(sacc[nj][3]),            \
                                            __float_as_uint(sacc[nj][2]), 0x07060302u); \
            _Pragma("unroll")                                                        \
            for (int nd = 0; nd < 4; ++nd) {                                         \
                const int d = nd * 16 + l15;                                         \
                const int vqb = nj * 2 + (lq >> 1);                                  \
                const int col = ((vqb ^ ((d >> 3) & 7)) << 2) | ((lq & 1) * 2);      \
                short4v aa = *(const short4v*)&VtsP[S][d][col];                      \
                o[nd] = __builtin_amdgcn_mfma_f32_16x16x16bf16_1k(aa, bp.s, o[nd], 0, 0, 0); \
            }                                                                        \
        }                                                                            \
        __builtin_amdgcn_s_setprio(0);                                               \
    }

__global__ __launch_bounds__(256)
void flash_attn_kernel(const UB* __restrict__ qkv, UB* __restrict__ outb)
{
    __shared__ UB Ks[2][64][72];               // 2 x 9216 B
    __shared__ unsigned int VtsP[2][64][36];   // 2 x 9216 B

    const int tid = threadIdx.x;
    const int lane = tid & 63;
    const int w = tid >> 6;
    const int l15 = lane & 15;
    const int lq = lane >> 4;
    const int lq8 = lq * 8;

    const int bh = blockIdx.x;              // b*16+h
    const int b = bh >> 4;
    const int h = bh & 15;
    const int by = blockIdx.y;              // 0..31
    const int qt = (by < 16) ? (2 * by + 1) : (62 - 2 * by);   // pairs sum to 31

    const UB* qbase = qkv + (size_t)(b * 2048) * 3072 + h * 64;
    const UB* kbase = qbase + 1024;
    const UB* vbase = qbase + 2048;

    const int q0w = qt * 64 + w * 16;       // wave's first Q row
    const int qrow = q0w + l15;             // lane's q row

    bf16x8 qf[2];
#pragma unroll
    for (int kk = 0; kk < 2; ++kk)
        qf[kk] = *(const bf16x8*)&qbase[(size_t)qrow * 3072 + kk * 32 + lq8];

    floatx4 o[4];                           // O^T: row d = nd*16+lq*4+r, col q = l15
#pragma unroll
    for (int nd = 0; nd < 4; ++nd) o[nd] = (floatx4){0.f, 0.f, 0.f, 0.f};
    float m_r = -1e30f, l_r = 0.f;

    const int krow = tid >> 3;
    const int kch8 = (tid & 7) * 8;
    const int vq = tid >> 3;
    const int vd0 = (tid & 7) * 8;
    const unsigned int vcol = ((((unsigned)vq >> 2) ^ (((unsigned)vd0 >> 3) & 7)) << 2) | (vq & 3);

    const UB* kp0 = kbase + (size_t)krow * 3072 + kch8;
    const UB* kp1 = kp0 + (size_t)32 * 3072;
    const UB* vp0 = vbase + (size_t)(2 * vq) * 3072 + vd0;
    const UB* vp1 = vp0 + 3072;

    const float SCL = 0.18033688011112042f;   // 0.125 * log2(e)

    // prologue: depth-2 prefetch (8 loads in flight)
    uint4 ka0 = *(const uint4*)kp0;
    uint4 kb0 = *(const uint4*)kp1;
    uint4 va0 = *(const uint4*)vp0;
    uint4 vb0 = *(const uint4*)vp1;
    const size_t off1 = (size_t)((qt >= 1) ? 1 : 0) * 196608;
    uint4 ka1 = *(const uint4*)(kp0 + off1);
    uint4 kb1 = *(const uint4*)(kp1 + off1);
    uint4 va1 = *(const uint4*)(vp0 + off1);
    uint4 vb1 = *(const uint4*)(vp1 + off1);

    for (int kt = 0; ; kt += 2) {
        FLASH_BODY(kt, 0, ka0, kb0, va0, vb0)
        if (kt == qt) break;
        FLASH_BODY(kt + 1, 1, ka1, kb1, va1, vb1)
        if (kt + 1 == qt) break;
    }

    {
        const float inv = 1.0f / l_r;
        UB* orow = outb + (size_t)(b * 2048 + qrow) * 1024 + h * 64;
#pragma unroll
        for (int nd = 0; nd < 4; ++nd) {
            UB o4[4];
#pragma unroll
            for (int r = 0; r < 4; ++r) o4[r] = f2bf(o[nd][r] * inv);
            *(ushort4*)&orow[nd * 16 + lq * 4] = *(ushort4*)o4;
        }
    }
}

// ---------- launch ----------
extern "C" void kernel_launch(void* const* d_in, const int* in_sizes, int n_in,
                              void* d_out, int out_size, void* d_ws, size_t ws_size,
                              hipStream_t stream) {
    const float* x        = (const float*)d_in[0];
    const float* c_attn_w = (const float*)d_in[1];
    const float* c_attn_b = (const float*)d_in[2];
    const float* c_proj_w = (const float*)d_in[3];
    const float* c_proj_b = (const float*)d_in[4];
    const float* mlp_w1   = (const float*)d_in[5];
    const float* mlp_b1   = (const float*)d_in[6];
    const float* mlp_w2   = (const float*)d_in[7];
    const float* mlp_b2   = (const float*)d_in[8];
    const float* ln1_g    = (const float*)d_in[9];
    const float* ln1_b    = (const float*)d_in[10];
    const float* ln2_g    = (const float*)d_in[11];
    const float* ln2_b    = (const float*)d_in[12];
    float* out = (float*)d_out;

    // workspace layout (bytes)
    char* ws = (char*)d_ws;
    UB*    ln_buf  = (UB*)(ws);                          //  8,388,608
    UB*    big_buf = (UB*)(ws + 8388608);                // 33,554,432 (qkv / proj-partial / h1)
    UB*    attout  = (UB*)(ws + 41943040);               //  8,388,608 (attn out / mlp2-partial-lo)
    float* x1      = (float*)(ws + 50331648);            // 16,777,216
    UB*    wt_attn = (UB*)(ws + 67108864);               //  6,291,456
    UB*    wt_proj = (UB*)(ws + 73400320);               //  2,097,152
    UB*    wt_mlp1 = (UB*)(ws + 75497472);               //  8,388,608
    UB*    wt_mlp2 = (UB*)(ws + 83886080);               //  8,388,608

    // 1. transpose weights fp32[K][N] -> bf16[N][K]
    transpose_w_kernel<<<dim3(96, 32), 256, 0, stream>>>(c_attn_w, wt_attn, 1024, 3072);
    transpose_w_kernel<<<dim3(32, 32), 256, 0, stream>>>(c_proj_w, wt_proj, 1024, 1024);
    transpose_w_kernel<<<dim3(128, 32), 256, 0, stream>>>(mlp_w1, wt_mlp1, 1024, 4096);
    transpose_w_kernel<<<dim3(32, 128), 256, 0, stream>>>(mlp_w2, wt_mlp2, 4096, 1024);

    // 2. LN1
    layernorm_kernel<<<4096, 256, 0, stream>>>(x, ln1_g, ln1_b, ln_buf);

    // 3. QKV = LN1 @ Wqkv + b : [4096][3072] bf16 (BN=128: 768 blocks, 3/CU exact)
    gemm_bt_kernel<0, 128, 3><<<dim3(24, 32, 1), 256, 0, stream>>>(ln_buf, wt_attn, c_attn_b,
                                                                   big_buf, nullptr, nullptr, 0,
                                                                   4096, 3072, 1024, 1024);

    // 4. attention (64-row Q tiles, 1024 blocks, 4/CU)
    flash_attn_kernel<<<dim3(32, 32), 256, 0, stream>>>(big_buf, attout);

    // 5. proj split-K=2 (BN=128, 512 blocks): z0 -> x1, z1 -> big_buf
    gemm_bt_kernel<4, 128, 3><<<dim3(8, 32, 2), 256, 0, stream>>>(attout, wt_proj, nullptr,
                                                                  x1, (float*)big_buf, (float*)big_buf, 4096,
                                                                  4096, 1024, 1024, 512);
    //    fused: x1 += partial + x + b_proj ; ln_buf = LN2(x1)
    reduce_ln_kernel<<<4096, 256, 0, stream>>>(x1, (float*)big_buf, (float*)big_buf, 4096,
                                               x, c_proj_b, ln2_g, ln2_b, ln_buf);

    // 7. h1 = gelu(LN2 @ W1 + b1) : bf16 [4096][4096]
    //    BN=128, OCC=4: 1024 blocks = 4/CU exact (32KB LDS x4 = 128KB, ~124 regs)
    gemm_bt_kernel<2, 128, 4><<<dim3(32, 32, 1), 256, 0, stream>>>(ln_buf, wt_mlp1, mlp_b1,
                                                                   big_buf, nullptr, nullptr, 0,
                                                                   4096, 4096, 1024, 1024);

    // 8. MLP2 split-K=2 (BN=128, 512 blocks): z0 -> out, z1 -> attout/ln_buf
    gemm_bt_kernel<4, 128, 3><<<dim3(8, 32, 2), 256, 0, stream>>>(big_buf, wt_mlp2, nullptr,
                                                                  out, (float*)attout, (float*)ln_buf, 2048,
                                                                  4096, 1024, 4096, 2048);
    //    out += partial + x1 + b2
    reduce_kernel<<<4096, 256, 0, stream>>>(out, (float*)attout, (float*)ln_buf, 2048,
                                            x1, mlp_b2);
}

// Round 5
// 306.375 us; speedup vs baseline: 1.0857x; 1.0857x over previous
//
#include <hip/hip_runtime.h>

typedef unsigned short UB;
typedef __attribute__((ext_vector_type(8))) __bf16 bf16x8;
typedef __attribute__((ext_vector_type(4))) __bf16 bf16x4;
typedef __attribute__((ext_vector_type(4))) float floatx4;
typedef __attribute__((ext_vector_type(4))) short short4v;

#define GAS __attribute__((address_space(1)))
#define LAS __attribute__((address_space(3)))

// ---------- helpers ----------
__device__ __forceinline__ UB f2bf(float f) {
    unsigned int x = __float_as_uint(f);
    unsigned int r = (x + 0x7fffu + ((x >> 16) & 1u)) >> 16;
    return (UB)r;
}

// fast gelu: tanh via exp2 + rcp (~11 VALU ops, err ~1e-6)
__device__ __forceinline__ float gelu_f(float v) {
    const float K = 2.3022083f;            // 2*sqrt(2/pi)*log2(e)
    const float v2 = v * v;
    const float u = v * fmaf(0.044715f, v2, 1.0f);
    float arg = K * u;
    arg = fminf(fmaxf(arg, -80.f), 80.f);  // v_med3
    const float e = __builtin_amdgcn_exp2f(arg);
    const float th = (e - 1.0f) * __builtin_amdgcn_rcpf(e + 1.0f);
    const float hv = 0.5f * v;
    return fmaf(hv, th, hv);
}

// async 16B global -> LDS (lds dest: wave-uniform base + lane*16)
__device__ __forceinline__ void gload16(const UB* g, UB* l) {
    __builtin_amdgcn_global_load_lds((const GAS unsigned int*)g,
                                     (LAS unsigned int*)l, 16, 0, 0);
}

// ---------- merged fp32 [K][N] -> bf16 [N][K] transpose for all 4 weights ----------
// one launch (12288 blocks) instead of 4: fewer launch gaps, packed tails.
__global__ __launch_bounds__(256)
void transpose_all_kernel(const float* __restrict__ Wa, const float* __restrict__ Wp,
                          const float* __restrict__ W1, const float* __restrict__ W2,
                          UB* __restrict__ Ta, UB* __restrict__ Tp,
                          UB* __restrict__ T1, UB* __restrict__ T2)
{
    __shared__ float tile[32][33];
    int id = blockIdx.x;
    const float* W; UB* Wt; int K, N, nbx;
    if (id < 3072)      {             W = Wa; Wt = Ta; K = 1024; N = 3072; nbx = 96; }
    else if (id < 4096) { id -= 3072; W = Wp; Wt = Tp; K = 1024; N = 1024; nbx = 32; }
    else if (id < 8192) { id -= 4096; W = W1; Wt = T1; K = 1024; N = 4096; nbx = 128; }
    else                { id -= 8192; W = W2; Wt = T2; K = 4096; N = 1024; nbx = 32; }
    const int n0 = (id % nbx) * 32;
    const int k0 = (id / nbx) * 32;
    const int x = threadIdx.x & 31;
    const int y = threadIdx.x >> 5;  // 0..7
#pragma unroll
    for (int j = 0; j < 32; j += 8)
        tile[y + j][x] = W[(size_t)(k0 + y + j) * N + n0 + x];
    __syncthreads();
#pragma unroll
    for (int j = 0; j < 32; j += 8)
        Wt[(size_t)(n0 + y + j) * K + k0 + x] = f2bf(tile[x][y + j]);
}

// ---------- LayerNorm fp32 -> bf16, one block per row, E=1024 ----------
__global__ __launch_bounds__(256)
void layernorm_kernel(const float* __restrict__ x, const float* __restrict__ g,
                      const float* __restrict__ bta, UB* __restrict__ out)
{
    __shared__ float red[8];
    const int row = blockIdx.x;
    const float* xr = x + (size_t)row * 1024;
    float v[4];
    float sum = 0.f, sumsq = 0.f;
#pragma unroll
    for (int i = 0; i < 4; ++i) {
        v[i] = xr[threadIdx.x + i * 256];
        sum += v[i];
        sumsq += v[i] * v[i];
    }
#pragma unroll
    for (int off = 32; off > 0; off >>= 1) {
        sum += __shfl_down(sum, off);
        sumsq += __shfl_down(sumsq, off);
    }
    const int w = threadIdx.x >> 6;
    if ((threadIdx.x & 63) == 0) { red[w * 2] = sum; red[w * 2 + 1] = sumsq; }
    __syncthreads();
    if (threadIdx.x == 0) {
        float s = 0.f, s2 = 0.f;
#pragma unroll
        for (int i = 0; i < 4; ++i) { s += red[i * 2]; s2 += red[i * 2 + 1]; }
        red[0] = s * (1.0f / 1024.0f);
        red[1] = s2 * (1.0f / 1024.0f);
    }
    __syncthreads();
    const float mu = red[0];
    const float var = red[1] - mu * mu;
    const float rs = rsqrtf(var + 1e-5f);
#pragma unroll
    for (int i = 0; i < 4; ++i) {
        const int e = threadIdx.x + i * 256;
        out[(size_t)row * 1024 + e] = f2bf((v[i] - mu) * rs * g[e] + bta[e]);
    }
}

// ---------- reduce: tgt += partial + res + bias  (fp32, N=1024) ----------
__global__ __launch_bounds__(256)
void reduce_kernel(float* __restrict__ tgt, const float* __restrict__ p_lo,
                   const float* __restrict__ p_hi, int rowSplit,
                   const float* __restrict__ res, const float* __restrict__ bias)
{
    const int i = blockIdx.x * 256 + threadIdx.x;  // float4 index
    const int row = i >> 8;
    const int col4 = i & 255;
    const float* p = (row < rowSplit) ? (p_lo + (size_t)row * 1024)
                                      : (p_hi + (size_t)(row - rowSplit) * 1024);
    const float4 t = ((const float4*)&tgt[(size_t)row * 1024])[col4];
    const float4 q = ((const float4*)p)[col4];
    const float4 r = ((const float4*)&res[(size_t)row * 1024])[col4];
    const float4 b = ((const float4*)bias)[col4];
    float4 o = make_float4(t.x + q.x + r.x + b.x, t.y + q.y + r.y + b.y,
                           t.z + q.z + r.z + b.z, t.w + q.w + r.w + b.w);
    ((float4*)&tgt[(size_t)row * 1024])[col4] = o;
}

// ---------- fused: x1 = x1 + partial + res + bias (store fp32), then LN -> bf16 ----------
__global__ __launch_bounds__(256)
void reduce_ln_kernel(float* __restrict__ tgt, const float* __restrict__ p_lo,
                      const float* __restrict__ p_hi, int rowSplit,
                      const float* __restrict__ res, const float* __restrict__ bias,
                      const float* __restrict__ g, const float* __restrict__ bta,
                      UB* __restrict__ outb)
{
    __shared__ float red[8];
    const int row = blockIdx.x;
    const int col4 = threadIdx.x;                  // float4 column
    const float* p = (row < rowSplit) ? (p_lo + (size_t)row * 1024)
                                      : (p_hi + (size_t)(row - rowSplit) * 1024);
    const float4 t = ((const float4*)&tgt[(size_t)row * 1024])[col4];
    const float4 q = ((const float4*)p)[col4];
    const float4 r = ((const float4*)&res[(size_t)row * 1024])[col4];
    const float4 b = ((const float4*)bias)[col4];
    float s[4];
    s[0] = t.x + q.x + r.x + b.x; s[1] = t.y + q.y + r.y + b.y;
    s[2] = t.z + q.z + r.z + b.z; s[3] = t.w + q.w + r.w + b.w;
    ((float4*)&tgt[(size_t)row * 1024])[col4] = make_float4(s[0], s[1], s[2], s[3]);

    float sum = s[0] + s[1] + s[2] + s[3];
    float sumsq = s[0]*s[0] + s[1]*s[1] + s[2]*s[2] + s[3]*s[3];
#pragma unroll
    for (int off = 32; off > 0; off >>= 1) {
        sum += __shfl_down(sum, off);
        sumsq += __shfl_down(sumsq, off);
    }
    const int w = threadIdx.x >> 6;
    if ((threadIdx.x & 63) == 0) { red[w * 2] = sum; red[w * 2 + 1] = sumsq; }
    __syncthreads();
    if (threadIdx.x == 0) {
        float a = 0.f, a2 = 0.f;
#pragma unroll
        for (int i = 0; i < 4; ++i) { a += red[i * 2]; a2 += red[i * 2 + 1]; }
        red[0] = a * (1.0f / 1024.0f);
        red[1] = a2 * (1.0f / 1024.0f);
    }
    __syncthreads();
    const float mu = red[0];
    const float var = red[1] - mu * mu;
    const float rs = rsqrtf(var + 1e-5f);
    const float4 gg = ((const float4*)g)[col4];
    const float4 bb = ((const float4*)bta)[col4];
    UB o4[4];
    o4[0] = f2bf((s[0] - mu) * rs * gg.x + bb.x);
    o4[1] = f2bf((s[1] - mu) * rs * gg.y + bb.y);
    o4[2] = f2bf((s[2] - mu) * rs * gg.z + bb.z);
    o4[3] = f2bf((s[3] - mu) * rs * gg.w + bb.w);
    *(ushort4*)&outb[(size_t)row * 1024 + col4 * 4] = *(ushort4*)o4;
}

// ---------- GEMM v5: v4 + XCD-footprint swizzle.
// All grids are fully co-resident (2-4 blocks/CU), so the lever is the SET of
// tiles per XCD (XCD = linear_wgid % 8, round-robin). Remap (bijective, all
// grids %8==0) so each XCD owns a compact m x n rectangle:
//   gz=1: 8m x (gx/2)n  (MLP1 A-traffic 64->16 MB; footprint 9->6 MB)
//   gz=2: z=xcd>>2, 8m x 8n  (MLP2 footprint 33->8 MB; proj 2 MB = L2-fit)
// If the XCD mapping assumption is wrong this is perf-neutral, never wrong.
// MODE 0: bf16 +bias   MODE 2: bf16 gelu(+bias)   MODE 4: split-K fp32 partial
template<int MODE, int BN, int OCC>
__global__ __launch_bounds__(256, OCC)
void gemm_bt_kernel(const UB* __restrict__ A, const UB* __restrict__ Bt,
                    const float* __restrict__ bias,
                    void* __restrict__ outp, float* __restrict__ pz_lo,
                    float* __restrict__ pz_hi, int rowSplit,
                    int M, int N, int K, int kLen)
{
    constexpr int NI = BN / 32;        // n-frags per wave per kk (4 or 8)
    constexpr int NB = BN / 32;        // B DMA instrs per thread (4 or 8)
    __shared__ UB As[128 * 64];        // 16 KB
    __shared__ UB Bs[BN * 64];         // 16/32 KB
    const int tid = threadIdx.x;
    const int lane = tid & 63;
    const int w = tid >> 6;
    const int l15 = lane & 15;
    const int lq = lane >> 4;
    const int wm = (w >> 1) * 64;
    const int wn = (w & 1) * (BN / 2);

    // XCD-footprint swizzle (gy == 32 in all our grids)
    const int lid = blockIdx.x + gridDim.x * (blockIdx.y + gridDim.y * blockIdx.z);
    const int xcd = lid & 7;
    const int r = lid >> 3;
    int m_t, n_t, z_t;
    if (gridDim.z == 1) {
        const int gxh = gridDim.x >> 1;
        m_t = (xcd >> 1) * 8 + (r & 7);
        n_t = (xcd & 1) * gxh + (r >> 3);
        z_t = 0;
    } else {                           // gz == 2, gx == 8
        m_t = (xcd & 3) * 8 + (r & 7);
        n_t = r >> 3;
        z_t = xcd >> 2;
    }
    const int m0 = m_t * 128;
    const int n0 = n_t * BN;
    const int kBase = z_t * kLen;
    const int e7 = l15 & 7;            // row&7 for all fragment rows

    // DMA pointers: A 4 instrs (1024 chunks), B NB instrs
    const UB* aG[4];
    UB* aL[4];
#pragma unroll
    for (int j = 0; j < 4; ++j) {
        const int c = j * 256 + w * 64 + lane;
        const int row = c >> 3;
        const int g = (c & 7) ^ (row & 7);
        aG[j] = A + (size_t)(m0 + row) * K + kBase + g * 8;
        aL[j] = As + (size_t)(j * 256 + w * 64) * 8;
    }
    const UB* bG[NB];
    UB* bL[NB];
#pragma unroll
    for (int j = 0; j < NB; ++j) {
        const int c = j * 256 + w * 64 + lane;
        const int row = c >> 3;
        const int g = (c & 7) ^ (row & 7);
        bG[j] = Bt + (size_t)(n0 + row) * K + kBase + g * 8;
        bL[j] = Bs + (size_t)(j * 256 + w * 64) * 8;
    }

    floatx4 acc[4][NI];
#pragma unroll
    for (int i = 0; i < 4; ++i)
#pragma unroll
        for (int j = 0; j < NI; ++j)
            acc[i][j] = (floatx4){0.f, 0.f, 0.f, 0.f};

    for (int ks = 0; ks < kLen; ks += 64) {
        __syncthreads();
#pragma unroll
        for (int j = 0; j < 4; ++j) gload16(aG[j] + ks, aL[j]);
#pragma unroll
        for (int j = 0; j < NB; ++j) gload16(bG[j] + ks, bL[j]);
        __syncthreads();

#pragma unroll
        for (int kk = 0; kk < 2; ++kk) {
            bf16x8 af[4], bfr[NI];
#pragma unroll
            for (int mi = 0; mi < 4; ++mi)
                af[mi] = *(const bf16x8*)&As[(wm + mi * 16 + l15) * 64 + (((kk * 4 + lq) ^ e7) * 8)];
#pragma unroll
            for (int ni = 0; ni < NI; ++ni)
                bfr[ni] = *(const bf16x8*)&Bs[(wn + ni * 16 + l15) * 64 + (((kk * 4 + lq) ^ e7) * 8)];
#pragma unroll
            for (int mi = 0; mi < 4; ++mi)
#pragma unroll
                for (int ni = 0; ni < NI; ++ni)
                    acc[mi][ni] = __builtin_amdgcn_mfma_f32_16x16x32_bf16(af[mi], bfr[ni], acc[mi][ni], 0, 0, 0);
        }
    }

    if (MODE == 4) {
        float* base;
        int roff;
        if (z_t == 0) { base = (float*)outp; roff = 0; }
        else if (m0 < rowSplit) { base = pz_lo; roff = 0; }
        else { base = pz_hi; roff = rowSplit; }
#pragma unroll
        for (int mi = 0; mi < 4; ++mi)
#pragma unroll
            for (int ni = 0; ni < NI; ++ni)
#pragma unroll
                for (int r2 = 0; r2 < 4; ++r2) {
                    const int row = m0 + wm + mi * 16 + lq * 4 + r2 - roff;
                    const int col = n0 + wn + ni * 16 + l15;
                    base[(size_t)row * N + col] = acc[mi][ni][r2];
                }
    } else {
#pragma unroll
        for (int mi = 0; mi < 4; ++mi)
#pragma unroll
            for (int ni = 0; ni < NI; ++ni)
#pragma unroll
                for (int r2 = 0; r2 < 4; ++r2) {
                    const int row = m0 + wm + mi * 16 + lq * 4 + r2;
                    const int col = n0 + wn + ni * 16 + l15;
                    float v = acc[mi][ni][r2] + bias[col];
                    if (MODE == 2) v = gelu_f(v);
                    ((UB*)outp)[(size_t)row * N + col] = f2bf(v);
                }
    }
}

// ---------- Flash attention v7 (causal): S^T trick, register-only P.
// v6 base (dbuf K/V LDS, depth-2 reg prefetch, one raw barrier/K-tile) plus:
//  - V-pack via v_perm, max3-tree mx reduce, pairwise-tree sl reduce
//  - defer-max (T13, thr=8, wave-uniform __any)
//  - s_setprio(1) around S-MFMA and PV-MFMA clusters (T5)
#define FLASH_BODY(KT, S, KA, KB, VA, VB)                                            \
    {                                                                                \
        const int kt_ = (KT);                                                        \
        /* stage tile kt into LDS buf S (compiler waits vmcnt for KA..VB only) */    \
        *(uint4*)&Ks[S][krow][kch8] = KA;                                            \
        *(uint4*)&Ks[S][krow + 32][kch8] = KB;                                       \
        {                                                                            \
            const unsigned* aw = (const unsigned*)&VA;                               \
            const unsigned* bw = (const unsigned*)&VB;                               \
            _Pragma("unroll")                                                        \
            for (int j = 0; j < 8; ++j)                                              \
                VtsP[S][vd0 + j][vcol] = __builtin_amdgcn_perm(                      \
                    bw[j >> 1], aw[j >> 1], (j & 1) ? 0x07060302u : 0x05040100u);    \
        }                                                                            \
        /* refill this reg set with tile kt+2 (clamped to qt) */                     \
        {                                                                            \
            const int t2 = (kt_ + 2 <= qt) ? (kt_ + 2) : qt;                         \
            const size_t off = (size_t)t2 * 196608;  /* 64*3072 */                   \
            KA = *(const uint4*)(kp0 + off);                                         \
            KB = *(const uint4*)(kp1 + off);                                         \
            VA = *(const uint4*)(vp0 + off);                                         \
            VB = *(const uint4*)(vp1 + off);                                         \
        }                                                                            \
        /* single barrier: drain LDS writes only; vmcnt stays in flight */           \
        asm volatile("s_waitcnt lgkmcnt(0)\n\ts_barrier" ::: "memory");              \
        const bool needmask = (kt_ == qt);                                           \
        floatx4 sacc[4];                                                             \
        __builtin_amdgcn_s_setprio(1);                                               \
        _Pragma("unroll")                                                            \
        for (int nj = 0; nj < 4; ++nj) {                                             \
            bf16x8 ak0 = *(const bf16x8*)&Ks[S][nj * 16 + l15][lq8];                 \
            bf16x8 ak1 = *(const bf16x8*)&Ks[S][nj * 16 + l15][32 + lq8];            \
            floatx4 acc = (floatx4){0.f, 0.f, 0.f, 0.f};                             \
            acc = __builtin_amdgcn_mfma_f32_16x16x32_bf16(ak0, qf[0], acc, 0, 0, 0); \
            acc = __builtin_amdgcn_mfma_f32_16x16x32_bf16(ak1, qf[1], acc, 0, 0, 0); \
            sacc[nj] = acc;                                                          \
        }                                                                            \
        __builtin_amdgcn_s_setprio(0);                                               \
        if (needmask) {                                                              \
            _Pragma("unroll")                                                        \
            for (int nj = 0; nj < 4; ++nj)                                           \
                _Pragma("unroll")                                                    \
                for (int r = 0; r < 4; ++r) {                                        \
                    const int kcol = kt_ * 64 + nj * 16 + lq * 4 + r;                \
                    if (kcol > qrow) sacc[nj][r] = -1e30f;                           \
                }                                                                    \
        }                                                                            \
        {                                                                            \
            /* max3-fused tree reduce, depth 3 */                                    \
            const float t0 = fmaxf(fmaxf(sacc[0][0], sacc[0][1]), sacc[0][2]);       \
            const float t1 = fmaxf(fmaxf(sacc[0][3], sacc[1][0]), sacc[1][1]);       \
            const float t2m = fmaxf(fmaxf(sacc[1][2], sacc[1][3]), sacc[2][0]);      \
            const float t3 = fmaxf(fmaxf(sacc[2][1], sacc[2][2]), sacc[2][3]);       \
            const float t4 = fmaxf(fmaxf(sacc[3][0], sacc[3][1]), sacc[3][2]);       \
            const float u0 = fmaxf(fmaxf(t0, t1), t2m);                              \
            const float u1 = fmaxf(fmaxf(t3, t4), sacc[3][3]);                       \
            float mx = fmaxf(u0, u1);                                                \
            mx = fmaxf(mx, __shfl_xor(mx, 16));                                      \
            mx = fmaxf(mx, __shfl_xor(mx, 32));                                      \
            const float mxs = mx * SCL;                                              \
            /* defer-max: only rescale when max grew by > 8 (wave-uniform) */        \
            if (__any(mxs > m_r + 8.0f)) {                                           \
                const float mnew = fmaxf(m_r, mxs);                                  \
                const float al = __builtin_amdgcn_exp2f(m_r - mnew);                 \
                m_r = mnew;                                                          \
                l_r *= al;                                                           \
                _Pragma("unroll")                                                    \
                for (int nd = 0; nd < 4; ++nd)                                       \
                    _Pragma("unroll")                                                \
                    for (int r = 0; r < 4; ++r) o[nd][r] *= al;                      \
            }                                                                        \
            _Pragma("unroll")                                                        \
            for (int nj = 0; nj < 4; ++nj)                                           \
                _Pragma("unroll")                                                    \
                for (int r = 0; r < 4; ++r)                                          \
                    sacc[nj][r] = __builtin_amdgcn_exp2f(fmaf(sacc[nj][r], SCL, -m_r)); \
            /* pairwise add tree, depth 4 */                                         \
            const float a0 = sacc[0][0] + sacc[0][1], a1 = sacc[0][2] + sacc[0][3];  \
            const float a2 = sacc[1][0] + sacc[1][1], a3 = sacc[1][2] + sacc[1][3];  \
            const float a4 = sacc[2][0] + sacc[2][1], a5 = sacc[2][2] + sacc[2][3];  \
            const float a6 = sacc[3][0] + sacc[3][1], a7 = sacc[3][2] + sacc[3][3];  \
            float sl = ((a0 + a1) + (a2 + a3)) + ((a4 + a5) + (a6 + a7));            \
            sl += __shfl_xor(sl, 16);                                                \
            sl += __shfl_xor(sl, 32);                                                \
            l_r += sl;                                                               \
        }                                                                            \
        __builtin_amdgcn_s_setprio(1);                                               \
        _Pragma("unroll")                                                            \
        for (int nj = 0; nj < 4; ++nj) {                                             \
            union { unsigned int u[2]; short4v s; } bp;                              \
            bp.u[0] = __builtin_amdgcn_perm(__float_as_uint(sacc[nj][1]),            \
                                            __float_as_uint(sacc[nj][0]), 0x07060302u); \
            bp.u[1] = __builtin_amdgcn_perm(__float_as_uint(sacc[nj][3]),            \
                                            __float_as_uint(sacc[nj][2]), 0x07060302u); \
            _Pragma("unroll")                                                        \
            for (int nd = 0; nd < 4; ++nd) {                                         \
                const int d = nd * 16 + l15;                                         \
                const int vqb = nj * 2 + (lq >> 1);                                  \
                const int col = ((vqb ^ ((d >> 3) & 7)) << 2) | ((lq & 1) * 2);      \
                short4v aa = *(const short4v*)&VtsP[S][d][col];                      \
                o[nd] = __builtin_amdgcn_mfma_f32_16x16x16bf16_1k(aa, bp.s, o[nd], 0, 0, 0); \
            }                                                                        \
        }                                                                            \
        __builtin_amdgcn_s_setprio(0);                                               \
    }

__global__ __launch_bounds__(256)
void flash_attn_kernel(const UB* __restrict__ qkv, UB* __restrict__ outb)
{
    __shared__ UB Ks[2][64][72];               // 2 x 9216 B
    __shared__ unsigned int VtsP[2][64][36];   // 2 x 9216 B

    const int tid = threadIdx.x;
    const int lane = tid & 63;
    const int w = tid >> 6;
    const int l15 = lane & 15;
    const int lq = lane >> 4;
    const int lq8 = lq * 8;

    const int bh = blockIdx.x;              // b*16+h
    const int b = bh >> 4;
    const int h = bh & 15;
    const int by = blockIdx.y;              // 0..31
    const int qt = (by < 16) ? (2 * by + 1) : (62 - 2 * by);   // pairs sum to 31

    const UB* qbase = qkv + (size_t)(b * 2048) * 3072 + h * 64;
    const UB* kbase = qbase + 1024;
    const UB* vbase = qbase + 2048;

    const int q0w = qt * 64 + w * 16;       // wave's first Q row
    const int qrow = q0w + l15;             // lane's q row

    bf16x8 qf[2];
#pragma unroll
    for (int kk = 0; kk < 2; ++kk)
        qf[kk] = *(const bf16x8*)&qbase[(size_t)qrow * 3072 + kk * 32 + lq8];

    floatx4 o[4];                           // O^T: row d = nd*16+lq*4+r, col q = l15
#pragma unroll
    for (int nd = 0; nd < 4; ++nd) o[nd] = (floatx4){0.f, 0.f, 0.f, 0.f};
    float m_r = -1e30f, l_r = 0.f;

    const int krow = tid >> 3;
    const int kch8 = (tid & 7) * 8;
    const int vq = tid >> 3;
    const int vd0 = (tid & 7) * 8;
    const unsigned int vcol = ((((unsigned)vq >> 2) ^ (((unsigned)vd0 >> 3) & 7)) << 2) | (vq & 3);

    const UB* kp0 = kbase + (size_t)krow * 3072 + kch8;
    const UB* kp1 = kp0 + (size_t)32 * 3072;
    const UB* vp0 = vbase + (size_t)(2 * vq) * 3072 + vd0;
    const UB* vp1 = vp0 + 3072;

    const float SCL = 0.18033688011112042f;   // 0.125 * log2(e)

    // prologue: depth-2 prefetch (8 loads in flight)
    uint4 ka0 = *(const uint4*)kp0;
    uint4 kb0 = *(const uint4*)kp1;
    uint4 va0 = *(const uint4*)vp0;
    uint4 vb0 = *(const uint4*)vp1;
    const size_t off1 = (size_t)((qt >= 1) ? 1 : 0) * 196608;
    uint4 ka1 = *(const uint4*)(kp0 + off1);
    uint4 kb1 = *(const uint4*)(kp1 + off1);
    uint4 va1 = *(const uint4*)(vp0 + off1);
    uint4 vb1 = *(const uint4*)(vp1 + off1);

    for (int kt = 0; ; kt += 2) {
        FLASH_BODY(kt, 0, ka0, kb0, va0, vb0)
        if (kt == qt) break;
        FLASH_BODY(kt + 1, 1, ka1, kb1, va1, vb1)
        if (kt + 1 == qt) break;
    }

    {
        const float inv = 1.0f / l_r;
        UB* orow = outb + (size_t)(b * 2048 + qrow) * 1024 + h * 64;
#pragma unroll
        for (int nd = 0; nd < 4; ++nd) {
            UB o4[4];
#pragma unroll
            for (int r = 0; r < 4; ++r) o4[r] = f2bf(o[nd][r] * inv);
            *(ushort4*)&orow[nd * 16 + lq * 4] = *(ushort4*)o4;
        }
    }
}

// ---------- launch ----------
extern "C" void kernel_launch(void* const* d_in, const int* in_sizes, int n_in,
                              void* d_out, int out_size, void* d_ws, size_t ws_size,
                              hipStream_t stream) {
    const float* x        = (const float*)d_in[0];
    const float* c_attn_w = (const float*)d_in[1];
    const float* c_attn_b = (const float*)d_in[2];
    const float* c_proj_w = (const float*)d_in[3];
    const float* c_proj_b = (const float*)d_in[4];
    const float* mlp_w1   = (const float*)d_in[5];
    const float* mlp_b1   = (const float*)d_in[6];
    const float* mlp_w2   = (const float*)d_in[7];
    const float* mlp_b2   = (const float*)d_in[8];
    const float* ln1_g    = (const float*)d_in[9];
    const float* ln1_b    = (const float*)d_in[10];
    const float* ln2_g    = (const float*)d_in[11];
    const float* ln2_b    = (const float*)d_in[12];
    float* out = (float*)d_out;

    // workspace layout (bytes)
    char* ws = (char*)d_ws;
    UB*    ln_buf  = (UB*)(ws);                          //  8,388,608
    UB*    big_buf = (UB*)(ws + 8388608);                // 33,554,432 (qkv / proj-partial / h1)
    UB*    attout  = (UB*)(ws + 41943040);               //  8,388,608 (attn out / mlp2-partial-lo)
    float* x1      = (float*)(ws + 50331648);            // 16,777,216
    UB*    wt_attn = (UB*)(ws + 67108864);               //  6,291,456
    UB*    wt_proj = (UB*)(ws + 73400320);               //  2,097,152
    UB*    wt_mlp1 = (UB*)(ws + 75497472);               //  8,388,608
    UB*    wt_mlp2 = (UB*)(ws + 83886080);               //  8,388,608

    // 1. transpose all weights fp32[K][N] -> bf16[N][K] in ONE launch
    transpose_all_kernel<<<12288, 256, 0, stream>>>(c_attn_w, c_proj_w, mlp_w1, mlp_w2,
                                                    wt_attn, wt_proj, wt_mlp1, wt_mlp2);

    // 2. LN1
    layernorm_kernel<<<4096, 256, 0, stream>>>(x, ln1_g, ln1_b, ln_buf);

    // 3. QKV = LN1 @ Wqkv + b : [4096][3072] bf16 (BN=128: 768 blocks, 3/CU exact)
    gemm_bt_kernel<0, 128, 3><<<dim3(24, 32, 1), 256, 0, stream>>>(ln_buf, wt_attn, c_attn_b,
                                                                   big_buf, nullptr, nullptr, 0,
                                                                   4096, 3072, 1024, 1024);

    // 4. attention (64-row Q tiles, 1024 blocks, 4/CU)
    flash_attn_kernel<<<dim3(32, 32), 256, 0, stream>>>(big_buf, attout);

    // 5. proj split-K=2 (BN=128, 512 blocks): z0 -> x1, z1 -> big_buf
    gemm_bt_kernel<4, 128, 3><<<dim3(8, 32, 2), 256, 0, stream>>>(attout, wt_proj, nullptr,
                                                                  x1, (float*)big_buf, (float*)big_buf, 4096,
                                                                  4096, 1024, 1024, 512);
    //    fused: x1 += partial + x + b_proj ; ln_buf = LN2(x1)
    reduce_ln_kernel<<<4096, 256, 0, stream>>>(x1, (float*)big_buf, (float*)big_buf, 4096,
                                               x, c_proj_b, ln2_g, ln2_b, ln_buf);

    // 7. h1 = gelu(LN2 @ W1 + b1) : bf16 [4096][4096]
    //    BN=128, OCC=4: 1024 blocks = 4/CU exact (32KB LDS x4 = 128KB, ~124 regs)
    gemm_bt_kernel<2, 128, 4><<<dim3(32, 32, 1), 256, 0, stream>>>(ln_buf, wt_mlp1, mlp_b1,
                                                                   big_buf, nullptr, nullptr, 0,
                                                                   4096, 4096, 1024, 1024);

    // 8. MLP2 split-K=2 (BN=128, 512 blocks): z0 -> out, z1 -> attout/ln_buf
    gemm_bt_kernel<4, 128, 3><<<dim3(8, 32, 2), 256, 0, stream>>>(big_buf, wt_mlp2, nullptr,
                                                                  out, (float*)attout, (float*)ln_buf, 2048,
                                                                  4096, 1024, 4096, 2048);
    //    out += partial + x1 + b2
    reduce_kernel<<<4096, 256, 0, stream>>>(out, (float*)attout, (float*)ln_buf, 2048,
                                            x1, mlp_b2);
}